// Round 2
// baseline (156.125 us; speedup 1.0000x reference)
//
#include <hip/hip_runtime.h>
#include <hip/hip_bf16.h>

#define EPS 1e-5f

typedef unsigned short u16;
typedef __attribute__((ext_vector_type(8))) __bf16 bf16x8;
typedef __attribute__((ext_vector_type(4))) float f32x4;
typedef __attribute__((ext_vector_type(8))) short short8;

// round-to-nearest-even f32 -> bf16
__device__ __forceinline__ u16 f2bf(float f) {
  unsigned int u = __float_as_uint(f);
  u += 0x7fffu + ((u >> 16) & 1u);
  return (u16)(u >> 16);
}

// ---------------------------------------------------------------------------
// prep kernel: blocks 0..127  -> L/R projections (layer-0 fold)
//              blocks 128..159 -> fold BN into G layers 1,2 (bf16 W + f32 bias)
// ---------------------------------------------------------------------------
__global__ __launch_bounds__(256) void prep(
    const float* __restrict__ x, const float* __restrict__ gW,
    const float* __restrict__ gb, const float* __restrict__ ggamma,
    const float* __restrict__ gbeta, const float* __restrict__ gmean,
    const float* __restrict__ gvar,
    u16* __restrict__ Wb, float* __restrict__ biasOut,
    float* __restrict__ Lf, float* __restrict__ Rf) {
  const int t = threadIdx.x;
  if (blockIdx.x >= 128) {
    // ---- fold part: 32 blocks, each 16 rows of one layer
    const int idx = blockIdx.x - 128;
    const int l = idx >> 4;                 // 0,1 -> g layer 1,2
    const int blk = idx & 15;
    const int gl = l + 1;
    const int row = blk * 16 + (t >> 4);
    const int c0 = (t & 15) * 16;
    const int gi = gl * 256 + row;
    const float s = ggamma[gi] * rsqrtf(gvar[gi] + EPS);
    if (c0 == 0) biasOut[l * 256 + row] = (gb[gi] - gmean[gi]) * s + gbeta[gi];
    const float* wrow = gW + (size_t)gi * 256;
    u16* orow = Wb + (size_t)l * 65536 + row * 256;
    #pragma unroll
    for (int c = 0; c < 16; ++c) orow[c0 + c] = f2bf(wrow[c0 + c] * s);
    return;
  }
  // ---- L/R part: 128 blocks = 32 batches x 4 chunks of 16 objects
  const int b = blockIdx.x >> 2;
  const int chunk = blockIdx.x & 3;
  __shared__ __align__(16) float xs[16][128];
  {
    const float4* src = (const float4*)(x + ((size_t)b * 64 + chunk * 16) * 128);
    float4* dst = (float4*)(&xs[0][0]);
    for (int idx = t; idx < 512; idx += 256) dst[idx] = src[idx];
  }
  __syncthreads();
  const int u = t;
  float accL[16], accR[16];
  #pragma unroll
  for (int nn = 0; nn < 16; ++nn) { accL[nn] = 0.f; accR[nn] = 0.f; }
  const float4* wl = (const float4*)(gW + (size_t)u * 256);
  const float4* wr = (const float4*)(gW + (size_t)u * 256 + 128);
  for (int d4 = 0; d4 < 32; ++d4) {
    const float4 a = wl[d4];
    const float4 c = wr[d4];
    #pragma unroll
    for (int nn = 0; nn < 16; ++nn) {
      const float4 xv = *((const float4*)&xs[nn][d4 * 4]);
      accL[nn] += a.x * xv.x + a.y * xv.y + a.z * xv.z + a.w * xv.w;
      accR[nn] += c.x * xv.x + c.y * xv.y + c.z * xv.z + c.w * xv.w;
    }
  }
  const float s = ggamma[u] * rsqrtf(gvar[u] + EPS);
  const float lb = (gb[u] - gmean[u]) * s + gbeta[u];
  const int n0 = chunk * 16;
  #pragma unroll
  for (int nn = 0; nn < 16; ++nn) {
    Lf[((size_t)b * 64 + n0 + nn) * 256 + u] = accL[nn] * s + lb;
    Rf[((size_t)b * 64 + n0 + nn) * 256 + u] = accR[nn] * s;
  }
}

// ---------------------------------------------------------------------------
// Main fused kernel: per (i, b): 64 pairs (i, j=0..63)
//   h  = relu(L_i + R_j)            -> LDS bf16 (XOR-swizzled), 32 KiB
//   h' = relu(W1b h + b1)           -> same LDS buffer (acc held in regs
//                                      across a barrier before overwrite)
//   out = relu(W2b h' + b2)         -> column-sum over pairs -> Spart[b,i]
// block = 256 threads = 4 waves; wave w owns output cols [w*64, w*64+64)
// ---------------------------------------------------------------------------
__global__ __launch_bounds__(256, 5) void rn_main(
    const float* __restrict__ Lf, const float* __restrict__ Rf,
    const u16* __restrict__ W1b, const u16* __restrict__ W2b,
    const float* __restrict__ biasg, float* __restrict__ Spart) {
  __shared__ __align__(16) u16 hbuf[64 * 256];   // 32 KiB, reused per layer
  char* hb = (char*)hbuf;
  const int b = blockIdx.y;
  const int i = blockIdx.x;
  const int t = threadIdx.x;
  const int wave = t >> 6;
  const int lane = t & 63;
  const int g = lane >> 4;
  const int r = lane & 15;

  // ---- Phase 0: assemble h[j][u] = relu(L[i][u] + R[j][u]) (bf16, swizzled)
  {
    const int j = t >> 2;
    const int c0 = (t & 3) * 64;
    const float4* lrow = (const float4*)(Lf + ((size_t)b * 64 + i) * 256 + c0);
    const float4* rrow = (const float4*)(Rf + ((size_t)b * 64 + j) * 256 + c0);
    const int swz = (j & 7) << 4;
    #pragma unroll
    for (int q = 0; q < 16; q += 2) {
      const float4 l0 = lrow[q];
      const float4 l1 = lrow[q + 1];
      const float4 r0 = rrow[q];
      const float4 r1 = rrow[q + 1];
      short8 pk;
      pk[0] = (short)f2bf(fmaxf(l0.x + r0.x, 0.f));
      pk[1] = (short)f2bf(fmaxf(l0.y + r0.y, 0.f));
      pk[2] = (short)f2bf(fmaxf(l0.z + r0.z, 0.f));
      pk[3] = (short)f2bf(fmaxf(l0.w + r0.w, 0.f));
      pk[4] = (short)f2bf(fmaxf(l1.x + r1.x, 0.f));
      pk[5] = (short)f2bf(fmaxf(l1.y + r1.y, 0.f));
      pk[6] = (short)f2bf(fmaxf(l1.z + r1.z, 0.f));
      pk[7] = (short)f2bf(fmaxf(l1.w + r1.w, 0.f));
      const int colb = (c0 + q * 4) * 2;
      *(short8*)(hb + (j * 512 + (colb ^ swz))) = pk;
    }
  }
  __syncthreads();

  const int kl = g * 8;
  const f32x4 zero4 = {0.f, 0.f, 0.f, 0.f};
  f32x4 acc[4][4];

  // ---- Layer A: h -> acc (weights W1b)
  {
    #pragma unroll
    for (int mt = 0; mt < 4; ++mt)
      #pragma unroll
      for (int nt = 0; nt < 4; ++nt) acc[mt][nt] = zero4;
    const bf16x8* wb = (const bf16x8*)W1b;
    #pragma unroll
    for (int kk = 0; kk < 8; ++kk) {
      const int k = kk * 32 + kl;
      bf16x8 bfrag[4];
      #pragma unroll
      for (int nt = 0; nt < 4; ++nt) {
        const int uo = wave * 64 + nt * 16 + r;
        bfrag[nt] = wb[uo * 32 + (k >> 3)];
      }
      #pragma unroll
      for (int mt = 0; mt < 4; ++mt) {
        const int row = mt * 16 + r;
        const bf16x8 afrag =
            *(const bf16x8*)(hb + (row * 512 + ((k * 2) ^ ((row & 7) << 4))));
        #pragma unroll
        for (int nt = 0; nt < 4; ++nt)
          acc[mt][nt] = __builtin_amdgcn_mfma_f32_16x16x32_bf16(
              afrag, bfrag[nt], acc[mt][nt], 0, 0, 0);
      }
    }
  }
  __syncthreads();  // all reads of h done -> safe to overwrite

  // ---- write h' = relu(acc + b1) into the SAME buffer
  {
    #pragma unroll
    for (int nt = 0; nt < 4; ++nt) {
      const int col = wave * 64 + nt * 16 + r;
      const float bias = biasg[col];
      #pragma unroll
      for (int mt = 0; mt < 4; ++mt) {
        #pragma unroll
        for (int reg = 0; reg < 4; ++reg) {
          const int row = mt * 16 + g * 4 + reg;
          const float v = fmaxf(acc[mt][nt][reg] + bias, 0.f);
          *(u16*)(hb + (row * 512 + ((col * 2) ^ ((row & 7) << 4)))) = f2bf(v);
        }
      }
    }
  }
  __syncthreads();

  // ---- Layer B: h' -> relu -> column sums -> Spart (plain stores)
  {
    #pragma unroll
    for (int mt = 0; mt < 4; ++mt)
      #pragma unroll
      for (int nt = 0; nt < 4; ++nt) acc[mt][nt] = zero4;
    const bf16x8* wb = (const bf16x8*)W2b;
    #pragma unroll
    for (int kk = 0; kk < 8; ++kk) {
      const int k = kk * 32 + kl;
      bf16x8 bfrag[4];
      #pragma unroll
      for (int nt = 0; nt < 4; ++nt) {
        const int uo = wave * 64 + nt * 16 + r;
        bfrag[nt] = wb[uo * 32 + (k >> 3)];
      }
      #pragma unroll
      for (int mt = 0; mt < 4; ++mt) {
        const int row = mt * 16 + r;
        const bf16x8 afrag =
            *(const bf16x8*)(hb + (row * 512 + ((k * 2) ^ ((row & 7) << 4))));
        #pragma unroll
        for (int nt = 0; nt < 4; ++nt)
          acc[mt][nt] = __builtin_amdgcn_mfma_f32_16x16x32_bf16(
              afrag, bfrag[nt], acc[mt][nt], 0, 0, 0);
      }
    }
    #pragma unroll
    for (int nt = 0; nt < 4; ++nt) {
      const int col = wave * 64 + nt * 16 + r;
      const float bias = biasg[256 + col];
      float cs = 0.f;
      #pragma unroll
      for (int mt = 0; mt < 4; ++mt)
        #pragma unroll
        for (int reg = 0; reg < 4; ++reg)
          cs += fmaxf(acc[mt][nt][reg] + bias, 0.f);
      cs += __shfl_xor(cs, 16, 64);
      cs += __shfl_xor(cs, 32, 64);
      if (lane < 16) Spart[(((size_t)b * 64 + i) * 256) + col] = cs;
    }
  }
}

// ---------------------------------------------------------------------------
// F head: per batch: reduce Spart over i, then fp32 2x(Linear+BN+ReLU) +
// final Linear(256->128)
// ---------------------------------------------------------------------------
__global__ __launch_bounds__(256) void head_kernel(
    const float* __restrict__ Spart, const float* __restrict__ fW,
    const float* __restrict__ fb, const float* __restrict__ fgamma,
    const float* __restrict__ fbeta, const float* __restrict__ fmean,
    const float* __restrict__ fvar, const float* __restrict__ foW,
    const float* __restrict__ fob, float* __restrict__ out) {
  const int b = blockIdx.x;
  const int u = threadIdx.x;
  __shared__ __align__(16) float h[256];
  float s0 = 0.f;
  const float* sp = Spart + (size_t)b * 64 * 256 + u;
  #pragma unroll 8
  for (int ii = 0; ii < 64; ++ii) s0 += sp[ii * 256];
  h[u] = s0;
  __syncthreads();
  for (int l = 0; l < 2; ++l) {
    const float4* wrow = (const float4*)(fW + ((size_t)l * 256 + u) * 256);
    float z = 0.f;
    #pragma unroll 8
    for (int q = 0; q < 64; ++q) {
      const float4 wv = wrow[q];
      const float4 hv = *((const float4*)&h[q * 4]);
      z += wv.x * hv.x + wv.y * hv.y + wv.z * hv.z + wv.w * hv.w;
    }
    z += fb[l * 256 + u];
    const int fi = l * 256 + u;
    const float s = fgamma[fi] * rsqrtf(fvar[fi] + EPS);
    z = (z - fmean[fi]) * s + fbeta[fi];
    z = fmaxf(z, 0.f);
    __syncthreads();
    h[u] = z;
    __syncthreads();
  }
  if (u < 128) {
    const float4* wrow = (const float4*)(foW + (size_t)u * 256);
    float z = 0.f;
    #pragma unroll 8
    for (int q = 0; q < 64; ++q) {
      const float4 wv = wrow[q];
      const float4 hv = *((const float4*)&h[q * 4]);
      z += wv.x * hv.x + wv.y * hv.y + wv.z * hv.z + wv.w * hv.w;
    }
    out[(size_t)b * 128 + u] = z + fob[u];
  }
}

extern "C" void kernel_launch(void* const* d_in, const int* in_sizes, int n_in,
                              void* d_out, int out_size, void* d_ws, size_t ws_size,
                              hipStream_t stream) {
  const float* x      = (const float*)d_in[0];
  const float* gW     = (const float*)d_in[1];
  const float* gb     = (const float*)d_in[2];
  const float* ggamma = (const float*)d_in[3];
  const float* gbeta  = (const float*)d_in[4];
  const float* gmean  = (const float*)d_in[5];
  const float* gvar   = (const float*)d_in[6];
  const float* fW     = (const float*)d_in[7];
  const float* fb     = (const float*)d_in[8];
  const float* fgamma = (const float*)d_in[9];
  const float* fbeta  = (const float*)d_in[10];
  const float* fmean  = (const float*)d_in[11];
  const float* fvar   = (const float*)d_in[12];
  const float* foW    = (const float*)d_in[13];
  const float* fob    = (const float*)d_in[14];

  // workspace layout
  u16* W1b = (u16*)d_ws;                  // 65536 bf16
  u16* W2b = W1b + 65536;                 // 65536 bf16
  float* biasg = (float*)(W2b + 65536);   // 512 f32
  float* Lfp = biasg + 512;               // 32*64*256 f32
  float* Rfp = Lfp + 32 * 64 * 256;       // 32*64*256 f32
  float* Spart = Rfp + 32 * 64 * 256;     // 32*64*256 f32

  prep<<<dim3(160), 256, 0, stream>>>(x, gW, gb, ggamma, gbeta, gmean, gvar,
                                      W1b, biasg, Lfp, Rfp);
  rn_main<<<dim3(64, 32), 256, 0, stream>>>(Lfp, Rfp, W1b, W2b, biasg, Spart);
  head_kernel<<<dim3(32), 256, 0, stream>>>(Spart, fW, fb, fgamma, fbeta,
                                            fmean, fvar, foW, fob,
                                            (float*)d_out);
}

// Round 3
// 137.524 us; speedup vs baseline: 1.1353x; 1.1353x over previous
//
#include <hip/hip_runtime.h>
#include <hip/hip_bf16.h>

#define EPS 1e-5f

typedef unsigned short u16;
typedef __attribute__((ext_vector_type(8))) __bf16 bf16x8;
typedef __attribute__((ext_vector_type(4))) float f32x4;
typedef __attribute__((ext_vector_type(8))) short short8;

// round-to-nearest-even f32 -> bf16
__device__ __forceinline__ u16 f2bf(float f) {
  unsigned int u = __float_as_uint(f);
  u += 0x7fffu + ((u >> 16) & 1u);
  return (u16)(u >> 16);
}

// ---------------------------------------------------------------------------
// prep kernel: blocks 0..127  -> L/R projections (layer-0 fold)
//              blocks 128..159 -> fold BN into G layers 1,2 (bf16 W + f32 bias)
// ---------------------------------------------------------------------------
__global__ __launch_bounds__(256) void prep(
    const float* __restrict__ x, const float* __restrict__ gW,
    const float* __restrict__ gb, const float* __restrict__ ggamma,
    const float* __restrict__ gbeta, const float* __restrict__ gmean,
    const float* __restrict__ gvar,
    u16* __restrict__ Wb, float* __restrict__ biasOut,
    float* __restrict__ Lf, float* __restrict__ Rf) {
  const int t = threadIdx.x;
  if (blockIdx.x >= 128) {
    // ---- fold part: 32 blocks, each 16 rows of one layer
    const int idx = blockIdx.x - 128;
    const int l = idx >> 4;                 // 0,1 -> g layer 1,2
    const int blk = idx & 15;
    const int gl = l + 1;
    const int row = blk * 16 + (t >> 4);
    const int c0 = (t & 15) * 16;
    const int gi = gl * 256 + row;
    const float s = ggamma[gi] * rsqrtf(gvar[gi] + EPS);
    if (c0 == 0) biasOut[l * 256 + row] = (gb[gi] - gmean[gi]) * s + gbeta[gi];
    const float* wrow = gW + (size_t)gi * 256;
    u16* orow = Wb + (size_t)l * 65536 + row * 256;
    #pragma unroll
    for (int c = 0; c < 16; ++c) orow[c0 + c] = f2bf(wrow[c0 + c] * s);
    return;
  }
  // ---- L/R part: 128 blocks = 32 batches x 4 chunks of 16 objects
  const int b = blockIdx.x >> 2;
  const int chunk = blockIdx.x & 3;
  __shared__ __align__(16) float xs[16][128];
  {
    const float4* src = (const float4*)(x + ((size_t)b * 64 + chunk * 16) * 128);
    float4* dst = (float4*)(&xs[0][0]);
    for (int idx = t; idx < 512; idx += 256) dst[idx] = src[idx];
  }
  __syncthreads();
  const int u = t;
  float accL[16], accR[16];
  #pragma unroll
  for (int nn = 0; nn < 16; ++nn) { accL[nn] = 0.f; accR[nn] = 0.f; }
  const float4* wl = (const float4*)(gW + (size_t)u * 256);
  const float4* wr = (const float4*)(gW + (size_t)u * 256 + 128);
  for (int d4 = 0; d4 < 32; ++d4) {
    const float4 a = wl[d4];
    const float4 c = wr[d4];
    #pragma unroll
    for (int nn = 0; nn < 16; ++nn) {
      const float4 xv = *((const float4*)&xs[nn][d4 * 4]);
      accL[nn] += a.x * xv.x + a.y * xv.y + a.z * xv.z + a.w * xv.w;
      accR[nn] += c.x * xv.x + c.y * xv.y + c.z * xv.z + c.w * xv.w;
    }
  }
  const float s = ggamma[u] * rsqrtf(gvar[u] + EPS);
  const float lb = (gb[u] - gmean[u]) * s + gbeta[u];
  const int n0 = chunk * 16;
  #pragma unroll
  for (int nn = 0; nn < 16; ++nn) {
    Lf[((size_t)b * 64 + n0 + nn) * 256 + u] = accL[nn] * s + lb;
    Rf[((size_t)b * 64 + n0 + nn) * 256 + u] = accR[nn] * s;
  }
}

// ---------------------------------------------------------------------------
// Main fused kernel: per (i, b): 64 pairs (i, j=0..63)
//   h  = relu(L_i + R_j)            -> LDS bf16 (XOR-swizzled), 32 KiB
//   h' = relu(W1b h + b1)           -> same LDS buffer (acc held in regs
//                                      across a barrier before overwrite)
//   out = relu(W2b h' + b2)         -> column-sum over pairs -> Spart[b,i]
// block = 256 threads = 4 waves; wave w owns output cols [w*64, w*64+64)
// __launch_bounds__(256,4): 4 waves/SIMD target -> <=128 VGPR cap (fits the
// natural ~88; (256,5) capped at 48 VGPR and spilled acc to scratch: 220 MB
// of scratch traffic per dispatch, 130 us. Do not raise the min-waves arg.)
// ---------------------------------------------------------------------------
__global__ __launch_bounds__(256, 4) void rn_main(
    const float* __restrict__ Lf, const float* __restrict__ Rf,
    const u16* __restrict__ W1b, const u16* __restrict__ W2b,
    const float* __restrict__ biasg, float* __restrict__ Spart) {
  __shared__ __align__(16) u16 hbuf[64 * 256];   // 32 KiB, reused per layer
  char* hb = (char*)hbuf;
  const int b = blockIdx.y;
  const int i = blockIdx.x;
  const int t = threadIdx.x;
  const int wave = t >> 6;
  const int lane = t & 63;
  const int g = lane >> 4;
  const int r = lane & 15;

  // ---- Phase 0: assemble h[j][u] = relu(L[i][u] + R[j][u]) (bf16, swizzled)
  {
    const int j = t >> 2;
    const int c0 = (t & 3) * 64;
    const float4* lrow = (const float4*)(Lf + ((size_t)b * 64 + i) * 256 + c0);
    const float4* rrow = (const float4*)(Rf + ((size_t)b * 64 + j) * 256 + c0);
    const int swz = (j & 7) << 4;
    #pragma unroll
    for (int q = 0; q < 16; q += 2) {
      const float4 l0 = lrow[q];
      const float4 l1 = lrow[q + 1];
      const float4 r0 = rrow[q];
      const float4 r1 = rrow[q + 1];
      short8 pk;
      pk[0] = (short)f2bf(fmaxf(l0.x + r0.x, 0.f));
      pk[1] = (short)f2bf(fmaxf(l0.y + r0.y, 0.f));
      pk[2] = (short)f2bf(fmaxf(l0.z + r0.z, 0.f));
      pk[3] = (short)f2bf(fmaxf(l0.w + r0.w, 0.f));
      pk[4] = (short)f2bf(fmaxf(l1.x + r1.x, 0.f));
      pk[5] = (short)f2bf(fmaxf(l1.y + r1.y, 0.f));
      pk[6] = (short)f2bf(fmaxf(l1.z + r1.z, 0.f));
      pk[7] = (short)f2bf(fmaxf(l1.w + r1.w, 0.f));
      const int colb = (c0 + q * 4) * 2;
      *(short8*)(hb + (j * 512 + (colb ^ swz))) = pk;
    }
  }
  __syncthreads();

  const int kl = g * 8;
  const f32x4 zero4 = {0.f, 0.f, 0.f, 0.f};
  f32x4 acc[4][4];

  // ---- Layer A: h -> acc (weights W1b)
  {
    #pragma unroll
    for (int mt = 0; mt < 4; ++mt)
      #pragma unroll
      for (int nt = 0; nt < 4; ++nt) acc[mt][nt] = zero4;
    const bf16x8* wb = (const bf16x8*)W1b;
    #pragma unroll
    for (int kk = 0; kk < 8; ++kk) {
      const int k = kk * 32 + kl;
      bf16x8 bfrag[4];
      #pragma unroll
      for (int nt = 0; nt < 4; ++nt) {
        const int uo = wave * 64 + nt * 16 + r;
        bfrag[nt] = wb[uo * 32 + (k >> 3)];
      }
      #pragma unroll
      for (int mt = 0; mt < 4; ++mt) {
        const int row = mt * 16 + r;
        const bf16x8 afrag =
            *(const bf16x8*)(hb + (row * 512 + ((k * 2) ^ ((row & 7) << 4))));
        #pragma unroll
        for (int nt = 0; nt < 4; ++nt)
          acc[mt][nt] = __builtin_amdgcn_mfma_f32_16x16x32_bf16(
              afrag, bfrag[nt], acc[mt][nt], 0, 0, 0);
      }
    }
  }
  __syncthreads();  // all reads of h done -> safe to overwrite

  // ---- write h' = relu(acc + b1) into the SAME buffer
  {
    #pragma unroll
    for (int nt = 0; nt < 4; ++nt) {
      const int col = wave * 64 + nt * 16 + r;
      const float bias = biasg[col];
      #pragma unroll
      for (int mt = 0; mt < 4; ++mt) {
        #pragma unroll
        for (int reg = 0; reg < 4; ++reg) {
          const int row = mt * 16 + g * 4 + reg;
          const float v = fmaxf(acc[mt][nt][reg] + bias, 0.f);
          *(u16*)(hb + (row * 512 + ((col * 2) ^ ((row & 7) << 4)))) = f2bf(v);
        }
      }
    }
  }
  __syncthreads();

  // ---- Layer B: h' -> relu -> column sums -> Spart (plain stores)
  {
    #pragma unroll
    for (int mt = 0; mt < 4; ++mt)
      #pragma unroll
      for (int nt = 0; nt < 4; ++nt) acc[mt][nt] = zero4;
    const bf16x8* wb = (const bf16x8*)W2b;
    #pragma unroll
    for (int kk = 0; kk < 8; ++kk) {
      const int k = kk * 32 + kl;
      bf16x8 bfrag[4];
      #pragma unroll
      for (int nt = 0; nt < 4; ++nt) {
        const int uo = wave * 64 + nt * 16 + r;
        bfrag[nt] = wb[uo * 32 + (k >> 3)];
      }
      #pragma unroll
      for (int mt = 0; mt < 4; ++mt) {
        const int row = mt * 16 + r;
        const bf16x8 afrag =
            *(const bf16x8*)(hb + (row * 512 + ((k * 2) ^ ((row & 7) << 4))));
        #pragma unroll
        for (int nt = 0; nt < 4; ++nt)
          acc[mt][nt] = __builtin_amdgcn_mfma_f32_16x16x32_bf16(
              afrag, bfrag[nt], acc[mt][nt], 0, 0, 0);
      }
    }
    #pragma unroll
    for (int nt = 0; nt < 4; ++nt) {
      const int col = wave * 64 + nt * 16 + r;
      const float bias = biasg[256 + col];
      float cs = 0.f;
      #pragma unroll
      for (int mt = 0; mt < 4; ++mt)
        #pragma unroll
        for (int reg = 0; reg < 4; ++reg)
          cs += fmaxf(acc[mt][nt][reg] + bias, 0.f);
      cs += __shfl_xor(cs, 16, 64);
      cs += __shfl_xor(cs, 32, 64);
      if (lane < 16) Spart[(((size_t)b * 64 + i) * 256) + col] = cs;
    }
  }
}

// ---------------------------------------------------------------------------
// F head: per batch: reduce Spart over i, then fp32 2x(Linear+BN+ReLU) +
// final Linear(256->128)
// ---------------------------------------------------------------------------
__global__ __launch_bounds__(256) void head_kernel(
    const float* __restrict__ Spart, const float* __restrict__ fW,
    const float* __restrict__ fb, const float* __restrict__ fgamma,
    const float* __restrict__ fbeta, const float* __restrict__ fmean,
    const float* __restrict__ fvar, const float* __restrict__ foW,
    const float* __restrict__ fob, float* __restrict__ out) {
  const int b = blockIdx.x;
  const int u = threadIdx.x;
  __shared__ __align__(16) float h[256];
  float s0 = 0.f;
  const float* sp = Spart + (size_t)b * 64 * 256 + u;
  #pragma unroll 8
  for (int ii = 0; ii < 64; ++ii) s0 += sp[ii * 256];
  h[u] = s0;
  __syncthreads();
  for (int l = 0; l < 2; ++l) {
    const float4* wrow = (const float4*)(fW + ((size_t)l * 256 + u) * 256);
    float z = 0.f;
    #pragma unroll 8
    for (int q = 0; q < 64; ++q) {
      const float4 wv = wrow[q];
      const float4 hv = *((const float4*)&h[q * 4]);
      z += wv.x * hv.x + wv.y * hv.y + wv.z * hv.z + wv.w * hv.w;
    }
    z += fb[l * 256 + u];
    const int fi = l * 256 + u;
    const float s = fgamma[fi] * rsqrtf(fvar[fi] + EPS);
    z = (z - fmean[fi]) * s + fbeta[fi];
    z = fmaxf(z, 0.f);
    __syncthreads();
    h[u] = z;
    __syncthreads();
  }
  if (u < 128) {
    const float4* wrow = (const float4*)(foW + (size_t)u * 256);
    float z = 0.f;
    #pragma unroll 8
    for (int q = 0; q < 64; ++q) {
      const float4 wv = wrow[q];
      const float4 hv = *((const float4*)&h[q * 4]);
      z += wv.x * hv.x + wv.y * hv.y + wv.z * hv.z + wv.w * hv.w;
    }
    out[(size_t)b * 128 + u] = z + fob[u];
  }
}

extern "C" void kernel_launch(void* const* d_in, const int* in_sizes, int n_in,
                              void* d_out, int out_size, void* d_ws, size_t ws_size,
                              hipStream_t stream) {
  const float* x      = (const float*)d_in[0];
  const float* gW     = (const float*)d_in[1];
  const float* gb     = (const float*)d_in[2];
  const float* ggamma = (const float*)d_in[3];
  const float* gbeta  = (const float*)d_in[4];
  const float* gmean  = (const float*)d_in[5];
  const float* gvar   = (const float*)d_in[6];
  const float* fW     = (const float*)d_in[7];
  const float* fb     = (const float*)d_in[8];
  const float* fgamma = (const float*)d_in[9];
  const float* fbeta  = (const float*)d_in[10];
  const float* fmean  = (const float*)d_in[11];
  const float* fvar   = (const float*)d_in[12];
  const float* foW    = (const float*)d_in[13];
  const float* fob    = (const float*)d_in[14];

  // workspace layout
  u16* W1b = (u16*)d_ws;                  // 65536 bf16
  u16* W2b = W1b + 65536;                 // 65536 bf16
  float* biasg = (float*)(W2b + 65536);   // 512 f32
  float* Lfp = biasg + 512;               // 32*64*256 f32
  float* Rfp = Lfp + 32 * 64 * 256;       // 32*64*256 f32
  float* Spart = Rfp + 32 * 64 * 256;     // 32*64*256 f32

  prep<<<dim3(160), 256, 0, stream>>>(x, gW, gb, ggamma, gbeta, gmean, gvar,
                                      W1b, biasg, Lfp, Rfp);
  rn_main<<<dim3(64, 32), 256, 0, stream>>>(Lfp, Rfp, W1b, W2b, biasg, Spart);
  head_kernel<<<dim3(32), 256, 0, stream>>>(Spart, fW, fb, fgamma, fbeta,
                                            fmean, fvar, foW, fob,
                                            (float*)d_out);
}

// Round 4
// 91.523 us; speedup vs baseline: 1.7059x; 1.5026x over previous
//
#include <hip/hip_runtime.h>
#include <hip/hip_bf16.h>

#define EPS 1e-5f

typedef unsigned short u16;
typedef __attribute__((ext_vector_type(8))) __bf16 bf16x8;
typedef __attribute__((ext_vector_type(4))) float f32x4;
typedef __attribute__((ext_vector_type(4))) unsigned short u16x4;

// round-to-nearest-even f32 -> bf16
__device__ __forceinline__ u16 f2bf(float f) {
  unsigned int u = __float_as_uint(f);
  u += 0x7fffu + ((u >> 16) & 1u);
  return (u16)(u >> 16);
}

// ---------------------------------------------------------------------------
// prep kernel: blocks 0..127  -> L/R projections (layer-0 fold)
//              blocks 128..159 -> fold BN into G layers 1,2 into a
//              FRAGMENT-MAJOR bf16 layout:
//   Wf[l][kk][cb][lane=g*16+r][e] = W_folded[u=cb*16+r][k=kk*32+g*8+e]
// so rn_main's per-wave fragment load is base + frag*1KB + lane*16B
// (fully coalesced; the old [u][k] layout made every load touch 64 lines).
// ---------------------------------------------------------------------------
__global__ __launch_bounds__(256) void prep(
    const float* __restrict__ x, const float* __restrict__ gW,
    const float* __restrict__ gb, const float* __restrict__ ggamma,
    const float* __restrict__ gbeta, const float* __restrict__ gmean,
    const float* __restrict__ gvar,
    u16* __restrict__ Wf, float* __restrict__ biasOut,
    float* __restrict__ Lf, float* __restrict__ Rf) {
  const int t = threadIdx.x;
  if (blockIdx.x >= 128) {
    // ---- fold part: 32 blocks, each 16 rows (u) of one layer
    const int idx = blockIdx.x - 128;
    const int l = idx >> 4;                 // 0,1 -> g layer 1,2
    const int blk = idx & 15;
    const int gl = l + 1;
    const int row = blk * 16 + (t >> 4);    // u
    const int c0 = (t & 15) * 16;
    const int gi = gl * 256 + row;
    const float s = ggamma[gi] * rsqrtf(gvar[gi] + EPS);
    if (c0 == 0) biasOut[l * 256 + row] = (gb[gi] - gmean[gi]) * s + gbeta[gi];
    const float* wrow = gW + (size_t)gi * 256;
    const int r = row & 15;
    const int cb = row >> 4;
    #pragma unroll
    for (int c = 0; c < 16; ++c) {
      const int k = c0 + c;
      const int kk = k >> 5;
      const int g = (k >> 3) & 3;
      const int e = k & 7;
      const size_t flat =
          (((((size_t)l * 8 + kk) * 16 + cb) * 64) + g * 16 + r) * 8 + e;
      Wf[flat] = f2bf(wrow[k] * s);
    }
    return;
  }
  // ---- L/R part: 128 blocks = 32 batches x 4 chunks of 16 objects
  const int b = blockIdx.x >> 2;
  const int chunk = blockIdx.x & 3;
  __shared__ __align__(16) float xs[16][128];
  {
    const float4* src = (const float4*)(x + ((size_t)b * 64 + chunk * 16) * 128);
    float4* dst = (float4*)(&xs[0][0]);
    for (int idx = t; idx < 512; idx += 256) dst[idx] = src[idx];
  }
  __syncthreads();
  const int u = t;
  float accL[16], accR[16];
  #pragma unroll
  for (int nn = 0; nn < 16; ++nn) { accL[nn] = 0.f; accR[nn] = 0.f; }
  const float4* wl = (const float4*)(gW + (size_t)u * 256);
  const float4* wr = (const float4*)(gW + (size_t)u * 256 + 128);
  for (int d4 = 0; d4 < 32; ++d4) {
    const float4 a = wl[d4];
    const float4 c = wr[d4];
    #pragma unroll
    for (int nn = 0; nn < 16; ++nn) {
      const float4 xv = *((const float4*)&xs[nn][d4 * 4]);
      accL[nn] += a.x * xv.x + a.y * xv.y + a.z * xv.z + a.w * xv.w;
      accR[nn] += c.x * xv.x + c.y * xv.y + c.z * xv.z + c.w * xv.w;
    }
  }
  const float s = ggamma[u] * rsqrtf(gvar[u] + EPS);
  const float lb = (gb[u] - gmean[u]) * s + gbeta[u];
  const int n0 = chunk * 16;
  #pragma unroll
  for (int nn = 0; nn < 16; ++nn) {
    Lf[((size_t)b * 64 + n0 + nn) * 256 + u] = accL[nn] * s + lb;
    Rf[((size_t)b * 64 + n0 + nn) * 256 + u] = accR[nn] * s;
  }
}

// ---------------------------------------------------------------------------
// Main fused kernel: per (i, b): 64 pairs (i, j=0..63)
//   h  = relu(L_i + R_j)            -> LDS bf16 (XOR-swizzled), 32 KiB
//   h' = relu(W1 h + b1)            -> same LDS buffer (regs across barrier)
//   out = relu(W2 h' + b2)          -> column-sum over pairs -> Spart[b,i]
// block = 256 threads = 4 waves; wave w owns output cols [w*64, w*64+64).
// Weight fragments come from the fragment-major Wf layout (coalesced 1KB
// bursts). __launch_bounds__(256,3): total reg cap ~168 >= natural ~152
// (88 VGPR + 64 AGPR acc) -> no spill; (256,4)'s cap of 128 TOTAL spilled
// ~24 regs -> 37MB scratch writes/dispatch. Cap is on VGPR+AGPR combined.
// ---------------------------------------------------------------------------
__global__ __launch_bounds__(256, 3) void rn_main(
    const float* __restrict__ Lf, const float* __restrict__ Rf,
    const u16* __restrict__ Wf, const float* __restrict__ biasg,
    float* __restrict__ Spart) {
  __shared__ __align__(16) u16 hbuf[64 * 256];   // 32 KiB, reused per layer
  char* hb = (char*)hbuf;
  const int b = blockIdx.y;
  const int i = blockIdx.x;
  const int t = threadIdx.x;
  const int wave = t >> 6;
  const int lane = t & 63;
  const int g = lane >> 4;
  const int r = lane & 15;

  // ---- Phase 0: h[j][c] = relu(L[i][c] + R[j][c]), coalesced:
  // lane owns cols [lane*4, lane*4+4); L row loaded once; 16 coalesced R rows.
  {
    const float4 lv = *(const float4*)(Lf + ((size_t)b * 64 + i) * 256 + lane * 4);
    const float4* rbase = (const float4*)(Rf + (size_t)b * 64 * 256);
    #pragma unroll
    for (int q = 0; q < 16; ++q) {
      const int j = q * 4 + wave;
      const float4 rv = rbase[(size_t)j * 64 + lane];
      u16x4 pk;
      pk[0] = f2bf(fmaxf(lv.x + rv.x, 0.f));
      pk[1] = f2bf(fmaxf(lv.y + rv.y, 0.f));
      pk[2] = f2bf(fmaxf(lv.z + rv.z, 0.f));
      pk[3] = f2bf(fmaxf(lv.w + rv.w, 0.f));
      *(u16x4*)(hb + (j * 512 + ((lane * 8) ^ ((j & 7) << 4)))) = pk;
    }
  }
  __syncthreads();

  const int kl = g * 8;
  const f32x4 zero4 = {0.f, 0.f, 0.f, 0.f};
  f32x4 acc[4][4];

  // ---- Layer A: h -> acc (weights Wf layer 0)
  {
    #pragma unroll
    for (int mt = 0; mt < 4; ++mt)
      #pragma unroll
      for (int nt = 0; nt < 4; ++nt) acc[mt][nt] = zero4;
    const bf16x8* wb = (const bf16x8*)Wf;            // layer 0 fragments
    #pragma unroll
    for (int kk = 0; kk < 8; ++kk) {
      const int k = kk * 32 + kl;
      bf16x8 bfrag[4];
      #pragma unroll
      for (int nt = 0; nt < 4; ++nt)
        bfrag[nt] = wb[(kk * 16 + wave * 4 + nt) * 64 + lane];
      #pragma unroll
      for (int mt = 0; mt < 4; ++mt) {
        const int row = mt * 16 + r;
        const bf16x8 afrag =
            *(const bf16x8*)(hb + (row * 512 + ((k * 2) ^ ((row & 7) << 4))));
        #pragma unroll
        for (int nt = 0; nt < 4; ++nt)
          acc[mt][nt] = __builtin_amdgcn_mfma_f32_16x16x32_bf16(
              afrag, bfrag[nt], acc[mt][nt], 0, 0, 0);
      }
    }
  }
  __syncthreads();  // all reads of h done -> safe to overwrite

  // ---- write h' = relu(acc + b1) into the SAME buffer
  {
    #pragma unroll
    for (int nt = 0; nt < 4; ++nt) {
      const int col = wave * 64 + nt * 16 + r;
      const float bias = biasg[col];
      #pragma unroll
      for (int mt = 0; mt < 4; ++mt) {
        #pragma unroll
        for (int reg = 0; reg < 4; ++reg) {
          const int row = mt * 16 + g * 4 + reg;
          const float v = fmaxf(acc[mt][nt][reg] + bias, 0.f);
          *(u16*)(hb + (row * 512 + ((col * 2) ^ ((row & 7) << 4)))) = f2bf(v);
        }
      }
    }
  }
  __syncthreads();

  // ---- Layer B: h' -> relu -> column sums -> Spart (plain stores)
  {
    #pragma unroll
    for (int mt = 0; mt < 4; ++mt)
      #pragma unroll
      for (int nt = 0; nt < 4; ++nt) acc[mt][nt] = zero4;
    const bf16x8* wb = (const bf16x8*)(Wf + 65536);  // layer 1 fragments
    #pragma unroll
    for (int kk = 0; kk < 8; ++kk) {
      const int k = kk * 32 + kl;
      bf16x8 bfrag[4];
      #pragma unroll
      for (int nt = 0; nt < 4; ++nt)
        bfrag[nt] = wb[(kk * 16 + wave * 4 + nt) * 64 + lane];
      #pragma unroll
      for (int mt = 0; mt < 4; ++mt) {
        const int row = mt * 16 + r;
        const bf16x8 afrag =
            *(const bf16x8*)(hb + (row * 512 + ((k * 2) ^ ((row & 7) << 4))));
        #pragma unroll
        for (int nt = 0; nt < 4; ++nt)
          acc[mt][nt] = __builtin_amdgcn_mfma_f32_16x16x32_bf16(
              afrag, bfrag[nt], acc[mt][nt], 0, 0, 0);
      }
    }
    #pragma unroll
    for (int nt = 0; nt < 4; ++nt) {
      const int col = wave * 64 + nt * 16 + r;
      const float bias = biasg[256 + col];
      float cs = 0.f;
      #pragma unroll
      for (int mt = 0; mt < 4; ++mt)
        #pragma unroll
        for (int reg = 0; reg < 4; ++reg)
          cs += fmaxf(acc[mt][nt][reg] + bias, 0.f);
      cs += __shfl_xor(cs, 16, 64);
      cs += __shfl_xor(cs, 32, 64);
      if (lane < 16) Spart[(((size_t)b * 64 + i) * 256) + col] = cs;
    }
  }
}

// ---------------------------------------------------------------------------
// F head: per batch: reduce Spart over i, then fp32 2x(Linear+BN+ReLU) +
// final Linear(256->128)
// ---------------------------------------------------------------------------
__global__ __launch_bounds__(256) void head_kernel(
    const float* __restrict__ Spart, const float* __restrict__ fW,
    const float* __restrict__ fb, const float* __restrict__ fgamma,
    const float* __restrict__ fbeta, const float* __restrict__ fmean,
    const float* __restrict__ fvar, const float* __restrict__ foW,
    const float* __restrict__ fob, float* __restrict__ out) {
  const int b = blockIdx.x;
  const int u = threadIdx.x;
  __shared__ __align__(16) float h[256];
  float s0 = 0.f;
  const float* sp = Spart + (size_t)b * 64 * 256 + u;
  #pragma unroll 8
  for (int ii = 0; ii < 64; ++ii) s0 += sp[ii * 256];
  h[u] = s0;
  __syncthreads();
  for (int l = 0; l < 2; ++l) {
    const float4* wrow = (const float4*)(fW + ((size_t)l * 256 + u) * 256);
    float z = 0.f;
    #pragma unroll 8
    for (int q = 0; q < 64; ++q) {
      const float4 wv = wrow[q];
      const float4 hv = *((const float4*)&h[q * 4]);
      z += wv.x * hv.x + wv.y * hv.y + wv.z * hv.z + wv.w * hv.w;
    }
    z += fb[l * 256 + u];
    const int fi = l * 256 + u;
    const float s = fgamma[fi] * rsqrtf(fvar[fi] + EPS);
    z = (z - fmean[fi]) * s + fbeta[fi];
    z = fmaxf(z, 0.f);
    __syncthreads();
    h[u] = z;
    __syncthreads();
  }
  if (u < 128) {
    const float4* wrow = (const float4*)(foW + (size_t)u * 256);
    float z = 0.f;
    #pragma unroll 8
    for (int q = 0; q < 64; ++q) {
      const float4 wv = wrow[q];
      const float4 hv = *((const float4*)&h[q * 4]);
      z += wv.x * hv.x + wv.y * hv.y + wv.z * hv.z + wv.w * hv.w;
    }
    out[(size_t)b * 128 + u] = z + fob[u];
  }
}

extern "C" void kernel_launch(void* const* d_in, const int* in_sizes, int n_in,
                              void* d_out, int out_size, void* d_ws, size_t ws_size,
                              hipStream_t stream) {
  const float* x      = (const float*)d_in[0];
  const float* gW     = (const float*)d_in[1];
  const float* gb     = (const float*)d_in[2];
  const float* ggamma = (const float*)d_in[3];
  const float* gbeta  = (const float*)d_in[4];
  const float* gmean  = (const float*)d_in[5];
  const float* gvar   = (const float*)d_in[6];
  const float* fW     = (const float*)d_in[7];
  const float* fb     = (const float*)d_in[8];
  const float* fgamma = (const float*)d_in[9];
  const float* fbeta  = (const float*)d_in[10];
  const float* fmean  = (const float*)d_in[11];
  const float* fvar   = (const float*)d_in[12];
  const float* foW    = (const float*)d_in[13];
  const float* fob    = (const float*)d_in[14];

  // workspace layout
  u16* Wf = (u16*)d_ws;                   // 2*65536 bf16, fragment-major
  float* biasg = (float*)(Wf + 2 * 65536);// 512 f32
  float* Lfp = biasg + 512;               // 32*64*256 f32
  float* Rfp = Lfp + 32 * 64 * 256;       // 32*64*256 f32
  float* Spart = Rfp + 32 * 64 * 256;     // 32*64*256 f32

  prep<<<dim3(160), 256, 0, stream>>>(x, gW, gb, ggamma, gbeta, gmean, gvar,
                                      Wf, biasg, Lfp, Rfp);
  rn_main<<<dim3(64, 32), 256, 0, stream>>>(Lfp, Rfp, Wf, biasg, Spart);
  head_kernel<<<dim3(32), 256, 0, stream>>>(Spart, fW, fb, fgamma, fbeta,
                                            fmean, fvar, foW, fob,
                                            (float*)d_out);
}